// Round 8
// baseline (406.828 us; speedup 1.0000x reference)
//
#include <hip/hip_runtime.h>
#include <hip/hip_bf16.h>
#include <math.h>

#define BB 4
#define QQ 75
#define NBQ 300        // BB*QQ
#define CC 640
#define HW 121
#define NW 5
#define KS 5
#define SS 25          // NW*KS
#define MS 605         // KS*HW
#define JT 3025        // NW*MS
#define BQ_PER_XCD 38  // ceil(300/8)

typedef __attribute__((ext_vector_type(8))) short short8;
typedef __attribute__((ext_vector_type(4))) float f32x4;

// workspace float offsets
#define OFF_SBF   0
#define SBF_F     (BB*JT*CC/2)            // bf16 storage
#define OFF_QBF   (OFF_SBF + SBF_F)
#define QBF_F     (NBQ*HW*CC/2)
#define OFF_P     (OFF_QBF + QBF_F)       // float4 partials [300][5][121]
// norm partials [400][4][128] f32 alias the pout region: dead before simi
// writes pout (stream-serialized); 204800 floats << 726000-float pout region.
#define OFF_NRM   OFF_P

__device__ __forceinline__ void async16(const void* g, void* l) {
    __builtin_amdgcn_global_load_lds(
        (const __attribute__((address_space(1))) unsigned int*)g,
        (__attribute__((address_space(3))) unsigned int*)l, 16, 0, 0);
}

// ---------------------------------------------------------------------------
// R5: prep split into two WIDE-GRID kernels. The old prep_kernel ran 400
// blocks on 256 CUs (1.5 blocks/CU, 1-2 waves/SIMD) with 320 chained scalar
// loads/thread -> latency-bound; it was the bulk of the constant 168 us
// (dur - simi) gap. norm_kernel: 1600 blocks, one (col, c-residue r) each.
// Bit-exact with the old code: partial A_r is the same ascending fmaf chain,
// and scale_kernel combines (A0+A2)+(A1+A3) = old T[0]+T[1] exactly.
__global__ void norm_kernel(const float* __restrict__ sup, const float* __restrict__ qry,
                            float* __restrict__ nrm, float* __restrict__ out)
{
    const int blk = blockIdx.x;          // 0..1599 = col*4 + r
    const int col = blk >> 2, r = blk & 3;
    const int hw  = threadIdx.x;         // 128
    if (blk == 0 && hw == 0) out[0] = 0.f;   // replaces memset dispatch
    const float* src = (col < BB * SS)
        ? sup + (size_t)col * (CC * HW)
        : qry + (size_t)(col - BB * SS) * (CC * HW);
    float ss = 0.f;
    if (hw < HW) {
        const float* p = src + hw;
#pragma unroll 16
        for (int i = 0; i < CC / 4; ++i) {
            const float v = p[(size_t)(r + i * 4) * HW];
            ss = fmaf(v, v, ss);
        }
    }
    nrm[((size_t)col * 4 + r) * 128 + hw] = ss;
}

// scale_kernel: 1600 blocks, one (col, c-quarter) each; finalize inv, then
// the verified 32-c LDS transpose + bf16 pack over this quarter's 160 c's.
__global__ void scale_kernel(const float* __restrict__ sup, const float* __restrict__ qry,
                             const float* __restrict__ nrm,
                             __hip_bfloat16* __restrict__ Sbf, __hip_bfloat16* __restrict__ Qbf)
{
    const int blk = blockIdx.x;      // 0..1599 = col*4 + qtr
    const int col = blk >> 2, qtr = blk & 3;
    const int t   = threadIdx.x;     // 256
    const float* src;
    __hip_bfloat16* dst;
    if (col < BB * SS) {
        const int b = col / SS, s = col % SS;
        const int n = s / KS, k = s % KS;
        src = sup + (size_t)col * (CC * HW);
        dst = Sbf + ((size_t)b * JT + n * MS + k * HW) * CC;
    } else {
        const int bq = col - BB * SS;
        src = qry + (size_t)bq * (CC * HW);
        dst = Qbf + (size_t)bq * (HW * CC);
    }

    __shared__ float inv[128];
    __shared__ float T[32][128];

    if (t < 128) {
        const float p0 = nrm[((size_t)col * 4 + 0) * 128 + t];
        const float p1 = nrm[((size_t)col * 4 + 1) * 128 + t];
        const float p2 = nrm[((size_t)col * 4 + 2) * 128 + t];
        const float p3 = nrm[((size_t)col * 4 + 3) * 128 + t];
        // (A0+A2)+(A1+A3) == old T[0]+T[1], bit-exact
        inv[t] = (t < HW) ? 1.f / (sqrtf((p0 + p2) + (p1 + p3)) + 1e-8f) : 0.f;
    }

    for (int it = 0; it < 5; ++it) {
        const int c0 = qtr * 160 + it * 32;
        __syncthreads();                 // first pass also fences inv[]
#pragma unroll
        for (int i = 0; i < 16; ++i) {
            int idx = t + i * 256;
            int cc = idx >> 7, hw = idx & 127;
            if (hw < HW) T[cc][hw] = src[(size_t)(c0 + cc) * HW + hw] * inv[hw];
        }
        __syncthreads();
        const int hw = t >> 1, half = t & 1;
        if (hw < HW) {
            __hip_bfloat16 hv[16];
#pragma unroll
            for (int i = 0; i < 16; ++i) hv[i] = __float2bfloat16(T[half * 16 + i][hw]);
            int4* op = reinterpret_cast<int4*>(dst + (size_t)hw * CC + c0 + half * 16);
            op[0] = reinterpret_cast<int4*>(hv)[0];
            op[1] = reinterpret_cast<int4*>(hv)[1];
        }
    }
}

// ---------------------------------------------------------------------------
// Per (bq, n): MFMA cosine GEMM, register-resident top3/argmax.
// R4 (kept): transposed epilogue - mfma(bf_support, af_query, acc) puts
// support j on the C/D ROW axis, query m on COL: lane-local top-3 over j,
// state 16 VGPR, no spill, 3 blocks/CU, bank-conflict-free 64B-row swizzle.
__launch_bounds__(256, 3)
__global__ void simi_kernel(const __hip_bfloat16* __restrict__ Sbf,
                            const __hip_bfloat16* __restrict__ Qbf,
                            float4* __restrict__ pout)
{
    const int xcd   = blockIdx.x & 7;
    const int local = blockIdx.x >> 3;      // 0..189
    const int n     = local % NW;
    const int bq    = xcd * BQ_PER_XCD + local / NW;
    if (bq >= NBQ) return;
    const int b   = bq / QQ;
    const int tid = threadIdx.x;
    const int lane = tid & 63, wid = tid >> 6;
    const int l15 = lane & 15, l4 = lane >> 4;
    const int wj0 = (wid & 1) * 64;    // wave support-row base (tile-local)
    const int wm0 = (wid >> 1) * 64;   // wave query-col base

    const unsigned short* qbase = (const unsigned short*)(Qbf + (size_t)bq * (HW * CC));
    const unsigned short* sbase = (const unsigned short*)(Sbf + ((size_t)b * JT + n * MS) * CC);

    __shared__ __align__(16) unsigned short AsBuf[2][128 * 32];  // query tile, 2 x 8 KB
    __shared__ __align__(16) unsigned short BsBuf[2][128 * 32];  // support tile, 2 x 8 KB

    const int srow = lane >> 2;                       // row within 16-row group
    const int kb   = (lane & 3) ^ ((lane >> 3) & 3);  // swizzled k-block (0..3)
    int aoff2[2];
#pragma unroll
    for (int g = 0; g < 2; ++g) {
        int arow = wid * 32 + g * 16 + srow;
        int grow = arow < HW ? arow : HW - 1;
        aoff2[g] = grow * CC + kb * 8;
    }
    int jb2[2];
#pragma unroll
    for (int g = 0; g < 2; ++g) jb2[g] = wid * 32 + g * 16 + srow;

    const int ldso_base = wid * 2048 + lane * 16;   // byte offset in 8 KB buffer

    // stage one (ms0, c0) chunk (k=32) into buffer nb: 4 async16 per wave
#define STAGE(ms0_, c0_, nb_)                                                        \
    {                                                                                \
        _Pragma("unroll")                                                            \
        for (int g = 0; g < 2; ++g) {                                                \
            const int ldso = ldso_base + g * 1024;                                   \
            async16(qbase + aoff2[g] + (c0_), (char*)&AsBuf[nb_][0] + ldso);         \
            int j_ = (ms0_) + jb2[g];                                                \
            int jc_ = j_ < MS ? j_ : MS - 1;                                         \
            async16(sbase + jc_ * CC + kb * 8 + (c0_), (char*)&BsBuf[nb_][0] + ldso);\
        }                                                                            \
    }

    // per-lane top-3 state: 4 m-slots only (transposed epilogue)
    float rt0[4], rt1[4], rt2[4]; int ra[4];
#pragma unroll
    for (int i = 0; i < 4; ++i) { rt0[i] = -INFINITY; rt1[i] = -INFINITY; rt2[i] = -INFINITY; ra[i] = 0; }

    f32x4 acc[4][4];   // [ji][qi]
#pragma unroll
    for (int ji = 0; ji < 4; ++ji)
#pragma unroll
        for (int qi = 0; qi < 4; ++qi)
#pragma unroll
            for (int r = 0; r < 4; ++r) acc[ji][qi][r] = 0.f;

    // prologue: stage chunk 0
    STAGE(0, 0, 0);
    int nb = 0;

    const int slot = l4 ^ ((l15 >> 1) & 3);           // read slot (0..3)
    const int aro  = (wm0 + l15) * 32 + slot * 8;     // ushort idx, + qi*512
    const int bro  = (wj0 + l15) * 32 + slot * 8;     // ushort idx, + ji*512

    // flat pipelined loop: chunk t -> ms0=(t/20)*128, c0=(t%20)*32
    for (int t = 0; t < 100; ++t) {
        const int tn = t + 1;
        if (tn < 100) {
            const int nms = (tn / 20) * 128;
            const int nc  = (tn % 20) * 32;
            STAGE(nms, nc, nb ^ 1);
            // wait only for chunk-t's 4 loads (issued one full iteration ago)
            asm volatile("s_waitcnt vmcnt(4)" ::: "memory");
        } else {
            asm volatile("s_waitcnt vmcnt(0)" ::: "memory");
        }
        __builtin_amdgcn_s_barrier();   // buffer nb fully resident for all waves

        // ---- compute from buffer nb: 8 fragment reads, 16 MFMA ----
        short8 af[4], bf[4];
#pragma unroll
        for (int qi = 0; qi < 4; ++qi)
            af[qi] = *(const short8*)(&AsBuf[nb][0] + aro + qi * 512);
#pragma unroll
        for (int ji = 0; ji < 4; ++ji)
            bf[ji] = *(const short8*)(&BsBuf[nb][0] + bro + ji * 512);

        __builtin_amdgcn_s_setprio(1);
#pragma unroll
        for (int ji = 0; ji < 4; ++ji)
#pragma unroll
            for (int qi = 0; qi < 4; ++qi)
                acc[ji][qi] = __builtin_amdgcn_mfma_f32_16x16x32_bf16(
                    bf[ji], af[qi], acc[ji][qi], 0, 0, 0);   // D[j, m]
        __builtin_amdgcn_s_setprio(0);
        nb ^= 1;

        if ((t % 20) == 19) {
            const int ms0 = (t / 20) * 128;
            // lane-local top-3 over this pass's 16 j-values per m-slot.
            // (ji, r) ascending == j ascending for fixed lane; strict >
            // keeps the first (smallest-j) max.
#pragma unroll
            for (int qi = 0; qi < 4; ++qi)
#pragma unroll
                for (int ji = 0; ji < 4; ++ji)
#pragma unroll
                    for (int r = 0; r < 4; ++r) {
                        const int jl = ms0 + wj0 + ji * 16 + l4 * 4 + r;
                        float v = (jl < MS) ? acc[ji][qi][r] : -INFINITY;
                        const bool gt = v > rt0[qi];
                        ra[qi] = gt ? (n * MS + jl) : ra[qi];
                        const float m1 = fminf(rt0[qi], v);
                        rt0[qi] = fmaxf(rt0[qi], v);
                        const float m2 = fminf(rt1[qi], m1);
                        rt1[qi] = fmaxf(rt1[qi], m1);
                        rt2[qi] = fmaxf(rt2[qi], m2);
                    }
            // re-zero accumulators for the next ms0 block
#pragma unroll
            for (int ji = 0; ji < 4; ++ji)
#pragma unroll
                for (int qi = 0; qi < 4; ++qi)
#pragma unroll
                    for (int r = 0; r < 4; ++r) acc[ji][qi][r] = 0.f;
        }

        __builtin_amdgcn_s_barrier();   // all reads of buffer nb^1 done before
                                        // anyone overwrites it next iteration
    }

    // cross-l4 butterfly (masks 16,32): merge the 4 j-interleaved partitions
#pragma unroll
    for (int qi = 0; qi < 4; ++qi) {
#pragma unroll
        for (int mask = 16; mask <= 32; mask <<= 1) {
            const float o0 = __shfl_xor(rt0[qi], mask);
            const float o1 = __shfl_xor(rt1[qi], mask);
            const float o2 = __shfl_xor(rt2[qi], mask);
            const int   oa = __shfl_xor(ra[qi],  mask);
            const bool take = (o0 > rt0[qi]) || (o0 == rt0[qi] && oa < ra[qi]);
            ra[qi] = take ? oa : ra[qi];
            float m1 = fminf(rt0[qi], o0); rt0[qi] = fmaxf(rt0[qi], o0);
            float m2 = fminf(rt1[qi], m1); rt1[qi] = fmaxf(rt1[qi], m1);
            rt2[qi] = fmaxf(rt2[qi], m2);
            m1 = fminf(rt0[qi], o1); rt0[qi] = fmaxf(rt0[qi], o1);
            m2 = fminf(rt1[qi], m1); rt1[qi] = fmaxf(rt1[qi], m1);
            rt2[qi] = fmaxf(rt2[qi], m2);
            m1 = fminf(rt0[qi], o2); rt0[qi] = fmaxf(rt0[qi], o2);
            m2 = fminf(rt1[qi], m1); rt1[qi] = fmaxf(rt1[qi], m1);
            rt2[qi] = fmaxf(rt2[qi], m2);
        }
    }

    // cross-wave merge: waves (wid, wid^1) share wm0, hold disjoint j-halves.
    __syncthreads();                       // all tile reads done -> safe overlay
    float4* mbuf = (float4*)&AsBuf[0][0];  // 128 float4 = 2 KB
    if ((wid & 1) == 0 && l4 == 0) {
#pragma unroll
        for (int qi = 0; qi < 4; ++qi) {
            float4 v; v.x = rt0[qi]; v.y = rt1[qi]; v.z = rt2[qi];
            v.w = __int_as_float(ra[qi]);
            mbuf[wm0 + qi * 16 + l15] = v;
        }
    }
    __syncthreads();
    if ((wid & 1) == 1 && l4 == 0) {
#pragma unroll
        for (int qi = 0; qi < 4; ++qi) {
            const int m = wm0 + qi * 16 + l15;
            const float4 o = mbuf[m];
            const int oa = __float_as_int(o.w);
            float s0 = rt0[qi], s1 = rt1[qi], s2 = rt2[qi]; int sa = ra[qi];
            const bool take = (o.x > s0) || (o.x == s0 && oa < sa);
            sa = take ? oa : sa;
            float m1 = fminf(s0, o.x); s0 = fmaxf(s0, o.x);
            float m2 = fminf(s1, m1);  s1 = fmaxf(s1, m1);
            s2 = fmaxf(s2, m2);
            m1 = fminf(s0, o.y); s0 = fmaxf(s0, o.y);
            m2 = fminf(s1, m1);  s1 = fmaxf(s1, m1);
            s2 = fmaxf(s2, m2);
            m1 = fminf(s0, o.z); s0 = fmaxf(s0, o.z);
            m2 = fminf(s1, m1);  s1 = fmaxf(s1, m1);
            s2 = fmaxf(s2, m2);
            if (m < HW) {
                float4 v; v.x = s0; v.y = s1; v.z = s2; v.w = __int_as_float(sa);
                pout[(bq * NW + n) * HW + m] = v;
            }
        }
    }
#undef STAGE
}

// ---------------------------------------------------------------------------
// Merge 5 per-n partials, mutual-NN mask, logits, per-query CE, atomic mean.
__global__ void merge_kernel(const float4* __restrict__ pout, const int* __restrict__ qy,
                             float* __restrict__ out)
{
    const int bq  = blockIdx.x;
    const int tid = threadIdx.x;   // 128 threads

    __shared__ float cw[128];
    __shared__ int   ag[128];
    __shared__ float tv[NW][128];
    __shared__ float maskf[128];
    __shared__ float lg[8];

    if (tid < HW) {
        float g0 = -INFINITY; int garg = 0;
#pragma unroll
        for (int n = 0; n < NW; ++n) {
            const float4 a = pout[(bq * NW + n) * HW + tid];
            if (a.x > g0) { g0 = a.x; garg = __float_as_int(a.w); }   // asc n = asc j
            tv[n][tid] = (a.x + a.y + a.z) * (1.f / 3.f);
        }
        cw[tid] = g0 + 1.0f;   // class_wise_max
        ag[tid] = garg;        // query_nearest (global j)
    }
    __syncthreads();
    if (tid < HW) {
        const float mycw = cw[tid];
        const int   myag = ag[tid];
        float ok = 1.f;
        for (int m2 = 0; m2 < HW; ++m2) {
            if (m2 == tid) continue;
            if (ag[m2] == myag) {
                float c2 = cw[m2];
                if (c2 > mycw || (c2 == mycw && m2 < tid)) ok = 0.f;  // first-max over mq
            }
        }
        maskf[tid] = ok;
    }
    __syncthreads();
    if (tid < NW) {
        float s = 0.f;
        for (int mq = 0; mq < HW; ++mq) s += maskf[mq] * tv[tid][mq];
        lg[tid] = s * 0.5f;   // / TEMPERATURE
    }
    __syncthreads();
    if (tid == 0) {
        float m = lg[0];
#pragma unroll
        for (int n2 = 1; n2 < NW; ++n2) m = fmaxf(m, lg[n2]);
        float se = 0.f;
#pragma unroll
        for (int n2 = 0; n2 < NW; ++n2) se += expf(lg[n2] - m);
        int y = qy[bq];
        atomicAdd(out, -(lg[y] - m - logf(se)) * (1.f / NBQ));
    }
}

// ---------------------------------------------------------------------------
extern "C" void kernel_launch(void* const* d_in, const int* in_sizes, int n_in,
                              void* d_out, int out_size, void* d_ws, size_t ws_size,
                              hipStream_t stream)
{
    const float* sup = (const float*)d_in[0];   // [4][25][640][121]
    const float* qry = (const float*)d_in[1];   // [4][75][640][121]
    const int*   qy  = (const int*)d_in[3];     // [4][75]
    float* out = (float*)d_out;
    float* ws  = (float*)d_ws;

    __hip_bfloat16* Sbf = (__hip_bfloat16*)(ws + OFF_SBF);
    __hip_bfloat16* Qbf = (__hip_bfloat16*)(ws + OFF_QBF);
    float4* pout = (float4*)(ws + OFF_P);
    float*  nrm  = (float*)(ws + OFF_NRM);   // aliases pout region (dead by then)

    hipLaunchKernelGGL(norm_kernel,  dim3((BB * SS + NBQ) * 4), dim3(128), 0, stream,
                       sup, qry, nrm, out);
    hipLaunchKernelGGL(scale_kernel, dim3((BB * SS + NBQ) * 4), dim3(256), 0, stream,
                       sup, qry, nrm, Sbf, Qbf);
    hipLaunchKernelGGL(simi_kernel, dim3(8 * BQ_PER_XCD * NW), dim3(256), 0, stream,
                       Sbf, Qbf, pout);
    hipLaunchKernelGGL(merge_kernel, dim3(NBQ), dim3(128), 0, stream, pout, qy, out);
}

// Round 9
// 402.307 us; speedup vs baseline: 1.0112x; 1.0112x over previous
//
#include <hip/hip_runtime.h>
#include <hip/hip_bf16.h>
#include <math.h>

#define BB 4
#define QQ 75
#define NBQ 300        // BB*QQ
#define CC 640
#define HW 121
#define NW 5
#define KS 5
#define SS 25          // NW*KS
#define MS 605         // KS*HW
#define JT 3025        // NW*MS
#define BQ_PER_XCD 38  // ceil(300/8)

typedef __attribute__((ext_vector_type(8))) short short8;
typedef __attribute__((ext_vector_type(4))) float f32x4;

// workspace float offsets
#define OFF_SBF   0
#define SBF_F     (BB*JT*CC/2)            // bf16 storage
#define OFF_QBF   (OFF_SBF + SBF_F)
#define QBF_F     (NBQ*HW*CC/2)
#define OFF_P     (OFF_QBF + QBF_F)       // float4 partials [300][5][121]
// norm partials [400][4][128] f32 alias the pout region: dead before simi
// writes pout (stream-serialized); 204800 floats << 726000-float pout region.
#define OFF_NRM   OFF_P

__device__ __forceinline__ void async16(const void* g, void* l) {
    __builtin_amdgcn_global_load_lds(
        (const __attribute__((address_space(1))) unsigned int*)g,
        (__attribute__((address_space(3))) unsigned int*)l, 16, 0, 0);
}

// ---------------------------------------------------------------------------
// Prep split (R5, kept: neutral vs monolithic, cleaner): norm_kernel computes
// per-(col, c-residue) sum-of-squares partials; bit-exact recombination in
// scale_kernel: (A0+A2)+(A1+A3) == old T[0]+T[1].
__global__ void norm_kernel(const float* __restrict__ sup, const float* __restrict__ qry,
                            float* __restrict__ nrm, float* __restrict__ out)
{
    const int blk = blockIdx.x;          // 0..1599 = col*4 + r
    const int col = blk >> 2, r = blk & 3;
    const int hw  = threadIdx.x;         // 128
    if (blk == 0 && hw == 0) out[0] = 0.f;   // replaces memset dispatch
    const float* src = (col < BB * SS)
        ? sup + (size_t)col * (CC * HW)
        : qry + (size_t)(col - BB * SS) * (CC * HW);
    float ss = 0.f;
    if (hw < HW) {
        const float* p = src + hw;
#pragma unroll 16
        for (int i = 0; i < CC / 4; ++i) {
            const float v = p[(size_t)(r + i * 4) * HW];
            ss = fmaf(v, v, ss);
        }
    }
    nrm[((size_t)col * 4 + r) * 128 + hw] = ss;
}

// scale_kernel: 1600 blocks, one (col, c-quarter) each; finalize inv, then
// the verified 32-c LDS transpose + bf16 pack over this quarter's 160 c's.
__global__ void scale_kernel(const float* __restrict__ sup, const float* __restrict__ qry,
                             const float* __restrict__ nrm,
                             __hip_bfloat16* __restrict__ Sbf, __hip_bfloat16* __restrict__ Qbf)
{
    const int blk = blockIdx.x;      // 0..1599 = col*4 + qtr
    const int col = blk >> 2, qtr = blk & 3;
    const int t   = threadIdx.x;     // 256
    const float* src;
    __hip_bfloat16* dst;
    if (col < BB * SS) {
        const int b = col / SS, s = col % SS;
        const int n = s / KS, k = s % KS;
        src = sup + (size_t)col * (CC * HW);
        dst = Sbf + ((size_t)b * JT + n * MS + k * HW) * CC;
    } else {
        const int bq = col - BB * SS;
        src = qry + (size_t)bq * (CC * HW);
        dst = Qbf + (size_t)bq * (HW * CC);
    }

    __shared__ float inv[128];
    __shared__ float T[32][128];

    if (t < 128) {
        const float p0 = nrm[((size_t)col * 4 + 0) * 128 + t];
        const float p1 = nrm[((size_t)col * 4 + 1) * 128 + t];
        const float p2 = nrm[((size_t)col * 4 + 2) * 128 + t];
        const float p3 = nrm[((size_t)col * 4 + 3) * 128 + t];
        // (A0+A2)+(A1+A3) == old T[0]+T[1], bit-exact
        inv[t] = (t < HW) ? 1.f / (sqrtf((p0 + p2) + (p1 + p3)) + 1e-8f) : 0.f;
    }

    for (int it = 0; it < 5; ++it) {
        const int c0 = qtr * 160 + it * 32;
        __syncthreads();                 // first pass also fences inv[]
#pragma unroll
        for (int i = 0; i < 16; ++i) {
            int idx = t + i * 256;
            int cc = idx >> 7, hw = idx & 127;
            if (hw < HW) T[cc][hw] = src[(size_t)(c0 + cc) * HW + hw] * inv[hw];
        }
        __syncthreads();
        const int hw = t >> 1, half = t & 1;
        if (hw < HW) {
            __hip_bfloat16 hv[16];
#pragma unroll
            for (int i = 0; i < 16; ++i) hv[i] = __float2bfloat16(T[half * 16 + i][hw]);
            int4* op = reinterpret_cast<int4*>(dst + (size_t)hw * CC + c0 + half * 16);
            op[0] = reinterpret_cast<int4*>(hv)[0];
            op[1] = reinterpret_cast<int4*>(hv)[1];
        }
    }
}

// ---------------------------------------------------------------------------
// Per (bq, n): MFMA cosine GEMM, register-resident top3/argmax (transposed
// epilogue, R4). R8 change: TRIPLE-BUFFER, ONE barrier per chunk (was 2).
// Hazard proof: a wave issues STAGE((t+1)%3) only after BAR(t-1); the only
// other reader of buf[(t+1)%3] is compute(t-2), whose ds_reads completed
// before that wave arrived at BAR(t-1) (lgkm waits precede its MFMAs). DMA
// visibility: per-wave vmcnt(4) before BAR(t) retires chunk-t's own loads;
// the barrier makes it global. Barrier count 200 -> 100 per block; counters
// showed matrix 28% + LDS 58% + VALU 5% with a 4x-slack wall -> barrier
// drain is the remaining unfalsified stall.
__launch_bounds__(256, 3)
__global__ void simi_kernel(const __hip_bfloat16* __restrict__ Sbf,
                            const __hip_bfloat16* __restrict__ Qbf,
                            float4* __restrict__ pout)
{
    const int xcd   = blockIdx.x & 7;
    const int local = blockIdx.x >> 3;      // 0..189
    const int n     = local % NW;
    const int bq    = xcd * BQ_PER_XCD + local / NW;
    if (bq >= NBQ) return;
    const int b   = bq / QQ;
    const int tid = threadIdx.x;
    const int lane = tid & 63, wid = tid >> 6;
    const int l15 = lane & 15, l4 = lane >> 4;
    const int wj0 = (wid & 1) * 64;    // wave support-row base (tile-local)
    const int wm0 = (wid >> 1) * 64;   // wave query-col base

    const unsigned short* qbase = (const unsigned short*)(Qbf + (size_t)bq * (HW * CC));
    const unsigned short* sbase = (const unsigned short*)(Sbf + ((size_t)b * JT + n * MS) * CC);

    __shared__ __align__(16) unsigned short AsBuf[3][128 * 32];  // query tile, 3 x 8 KB
    __shared__ __align__(16) unsigned short BsBuf[3][128 * 32];  // support tile, 3 x 8 KB

    const int srow = lane >> 2;                       // row within 16-row group
    const int kb   = (lane & 3) ^ ((lane >> 3) & 3);  // swizzled k-block (0..3)
    int aoff2[2];
#pragma unroll
    for (int g = 0; g < 2; ++g) {
        int arow = wid * 32 + g * 16 + srow;
        int grow = arow < HW ? arow : HW - 1;
        aoff2[g] = grow * CC + kb * 8;
    }
    int jb2[2];
#pragma unroll
    for (int g = 0; g < 2; ++g) jb2[g] = wid * 32 + g * 16 + srow;

    const int ldso_base = wid * 2048 + lane * 16;   // byte offset in 8 KB buffer

    // stage one (ms0, c0) chunk (k=32) into buffer nb: 4 async16 per wave
#define STAGE(ms0_, c0_, nb_)                                                        \
    {                                                                                \
        _Pragma("unroll")                                                            \
        for (int g = 0; g < 2; ++g) {                                                \
            const int ldso = ldso_base + g * 1024;                                   \
            async16(qbase + aoff2[g] + (c0_), (char*)&AsBuf[nb_][0] + ldso);         \
            int j_ = (ms0_) + jb2[g];                                                \
            int jc_ = j_ < MS ? j_ : MS - 1;                                         \
            async16(sbase + jc_ * CC + kb * 8 + (c0_), (char*)&BsBuf[nb_][0] + ldso);\
        }                                                                            \
    }

    // per-lane top-3 state: 4 m-slots only (transposed epilogue)
    float rt0[4], rt1[4], rt2[4]; int ra[4];
#pragma unroll
    for (int i = 0; i < 4; ++i) { rt0[i] = -INFINITY; rt1[i] = -INFINITY; rt2[i] = -INFINITY; ra[i] = 0; }

    f32x4 acc[4][4];   // [ji][qi]
#pragma unroll
    for (int ji = 0; ji < 4; ++ji)
#pragma unroll
        for (int qi = 0; qi < 4; ++qi)
#pragma unroll
            for (int r = 0; r < 4; ++r) acc[ji][qi][r] = 0.f;

    // prologue: stage chunk 0 into buffer 0
    STAGE(0, 0, 0);
    int nb = 0;

    const int slot = l4 ^ ((l15 >> 1) & 3);           // read slot (0..3)
    const int aro  = (wm0 + l15) * 32 + slot * 8;     // ushort idx, + qi*512
    const int bro  = (wj0 + l15) * 32 + slot * 8;     // ushort idx, + ji*512

    // flat pipelined loop: chunk t -> ms0=(t/20)*128, c0=(t%20)*32
    // read buf t%3, stage (t+1)%3; ONE barrier per chunk (see header proof)
    for (int t = 0; t < 100; ++t) {
        const int tn = t + 1;
        const int nxt = (nb == 2) ? 0 : nb + 1;
        if (tn < 100) {
            const int nms = (tn / 20) * 128;
            const int nc  = (tn % 20) * 32;
            STAGE(nms, nc, nxt);
            // wait only for chunk-t's 4 loads (issued one full chunk ago);
            // the 4 just-issued prefetch loads stay in flight across the barrier
            asm volatile("s_waitcnt vmcnt(4)" ::: "memory");
        } else {
            asm volatile("s_waitcnt vmcnt(0)" ::: "memory");
        }
        __builtin_amdgcn_s_barrier();   // buffer nb fully resident for all waves

        // ---- compute from buffer nb: 8 fragment reads, 16 MFMA ----
        short8 af[4], bf[4];
#pragma unroll
        for (int qi = 0; qi < 4; ++qi)
            af[qi] = *(const short8*)(&AsBuf[nb][0] + aro + qi * 512);
#pragma unroll
        for (int ji = 0; ji < 4; ++ji)
            bf[ji] = *(const short8*)(&BsBuf[nb][0] + bro + ji * 512);

        __builtin_amdgcn_s_setprio(1);
#pragma unroll
        for (int ji = 0; ji < 4; ++ji)
#pragma unroll
            for (int qi = 0; qi < 4; ++qi)
                acc[ji][qi] = __builtin_amdgcn_mfma_f32_16x16x32_bf16(
                    bf[ji], af[qi], acc[ji][qi], 0, 0, 0);   // D[j, m]
        __builtin_amdgcn_s_setprio(0);
        nb = nxt;

        if ((t % 20) == 19) {
            const int ms0 = (t / 20) * 128;
            // lane-local top-3 over this pass's 16 j-values per m-slot.
            // (ji, r) ascending == j ascending for fixed lane; strict >
            // keeps the first (smallest-j) max.
#pragma unroll
            for (int qi = 0; qi < 4; ++qi)
#pragma unroll
                for (int ji = 0; ji < 4; ++ji)
#pragma unroll
                    for (int r = 0; r < 4; ++r) {
                        const int jl = ms0 + wj0 + ji * 16 + l4 * 4 + r;
                        float v = (jl < MS) ? acc[ji][qi][r] : -INFINITY;
                        const bool gt = v > rt0[qi];
                        ra[qi] = gt ? (n * MS + jl) : ra[qi];
                        const float m1 = fminf(rt0[qi], v);
                        rt0[qi] = fmaxf(rt0[qi], v);
                        const float m2 = fminf(rt1[qi], m1);
                        rt1[qi] = fmaxf(rt1[qi], m1);
                        rt2[qi] = fmaxf(rt2[qi], m2);
                    }
            // re-zero accumulators for the next ms0 block
#pragma unroll
            for (int ji = 0; ji < 4; ++ji)
#pragma unroll
                for (int qi = 0; qi < 4; ++qi)
#pragma unroll
                    for (int r = 0; r < 4; ++r) acc[ji][qi][r] = 0.f;
        }
    }

    // cross-l4 butterfly (masks 16,32): merge the 4 j-interleaved partitions
#pragma unroll
    for (int qi = 0; qi < 4; ++qi) {
#pragma unroll
        for (int mask = 16; mask <= 32; mask <<= 1) {
            const float o0 = __shfl_xor(rt0[qi], mask);
            const float o1 = __shfl_xor(rt1[qi], mask);
            const float o2 = __shfl_xor(rt2[qi], mask);
            const int   oa = __shfl_xor(ra[qi],  mask);
            const bool take = (o0 > rt0[qi]) || (o0 == rt0[qi] && oa < ra[qi]);
            ra[qi] = take ? oa : ra[qi];
            float m1 = fminf(rt0[qi], o0); rt0[qi] = fmaxf(rt0[qi], o0);
            float m2 = fminf(rt1[qi], m1); rt1[qi] = fmaxf(rt1[qi], m1);
            rt2[qi] = fmaxf(rt2[qi], m2);
            m1 = fminf(rt0[qi], o1); rt0[qi] = fmaxf(rt0[qi], o1);
            m2 = fminf(rt1[qi], m1); rt1[qi] = fmaxf(rt1[qi], m1);
            rt2[qi] = fmaxf(rt2[qi], m2);
            m1 = fminf(rt0[qi], o2); rt0[qi] = fmaxf(rt0[qi], o2);
            m2 = fminf(rt1[qi], m1); rt1[qi] = fmaxf(rt1[qi], m1);
            rt2[qi] = fmaxf(rt2[qi], m2);
        }
    }

    // cross-wave merge: waves (wid, wid^1) share wm0, hold disjoint j-halves.
    __syncthreads();                       // all tile reads done -> safe overlay
    float4* mbuf = (float4*)&AsBuf[0][0];  // 128 float4 = 2 KB
    if ((wid & 1) == 0 && l4 == 0) {
#pragma unroll
        for (int qi = 0; qi < 4; ++qi) {
            float4 v; v.x = rt0[qi]; v.y = rt1[qi]; v.z = rt2[qi];
            v.w = __int_as_float(ra[qi]);
            mbuf[wm0 + qi * 16 + l15] = v;
        }
    }
    __syncthreads();
    if ((wid & 1) == 1 && l4 == 0) {
#pragma unroll
        for (int qi = 0; qi < 4; ++qi) {
            const int m = wm0 + qi * 16 + l15;
            const float4 o = mbuf[m];
            const int oa = __float_as_int(o.w);
            float s0 = rt0[qi], s1 = rt1[qi], s2 = rt2[qi]; int sa = ra[qi];
            const bool take = (o.x > s0) || (o.x == s0 && oa < sa);
            sa = take ? oa : sa;
            float m1 = fminf(s0, o.x); s0 = fmaxf(s0, o.x);
            float m2 = fminf(s1, m1);  s1 = fmaxf(s1, m1);
            s2 = fmaxf(s2, m2);
            m1 = fminf(s0, o.y); s0 = fmaxf(s0, o.y);
            m2 = fminf(s1, m1);  s1 = fmaxf(s1, m1);
            s2 = fmaxf(s2, m2);
            m1 = fminf(s0, o.z); s0 = fmaxf(s0, o.z);
            m2 = fminf(s1, m1);  s1 = fmaxf(s1, m1);
            s2 = fmaxf(s2, m2);
            if (m < HW) {
                float4 v; v.x = s0; v.y = s1; v.z = s2; v.w = __int_as_float(sa);
                pout[(bq * NW + n) * HW + m] = v;
            }
        }
    }
#undef STAGE
}

// ---------------------------------------------------------------------------
// Merge 5 per-n partials, mutual-NN mask, logits, per-query CE, atomic mean.
__global__ void merge_kernel(const float4* __restrict__ pout, const int* __restrict__ qy,
                             float* __restrict__ out)
{
    const int bq  = blockIdx.x;
    const int tid = threadIdx.x;   // 128 threads

    __shared__ float cw[128];
    __shared__ int   ag[128];
    __shared__ float tv[NW][128];
    __shared__ float maskf[128];
    __shared__ float lg[8];

    if (tid < HW) {
        float g0 = -INFINITY; int garg = 0;
#pragma unroll
        for (int n = 0; n < NW; ++n) {
            const float4 a = pout[(bq * NW + n) * HW + tid];
            if (a.x > g0) { g0 = a.x; garg = __float_as_int(a.w); }   // asc n = asc j
            tv[n][tid] = (a.x + a.y + a.z) * (1.f / 3.f);
        }
        cw[tid] = g0 + 1.0f;   // class_wise_max
        ag[tid] = garg;        // query_nearest (global j)
    }
    __syncthreads();
    if (tid < HW) {
        const float mycw = cw[tid];
        const int   myag = ag[tid];
        float ok = 1.f;
        for (int m2 = 0; m2 < HW; ++m2) {
            if (m2 == tid) continue;
            if (ag[m2] == myag) {
                float c2 = cw[m2];
                if (c2 > mycw || (c2 == mycw && m2 < tid)) ok = 0.f;  // first-max over mq
            }
        }
        maskf[tid] = ok;
    }
    __syncthreads();
    if (tid < NW) {
        float s = 0.f;
        for (int mq = 0; mq < HW; ++mq) s += maskf[mq] * tv[tid][mq];
        lg[tid] = s * 0.5f;   // / TEMPERATURE
    }
    __syncthreads();
    if (tid == 0) {
        float m = lg[0];
#pragma unroll
        for (int n2 = 1; n2 < NW; ++n2) m = fmaxf(m, lg[n2]);
        float se = 0.f;
#pragma unroll
        for (int n2 = 0; n2 < NW; ++n2) se += expf(lg[n2] - m);
        int y = qy[bq];
        atomicAdd(out, -(lg[y] - m - logf(se)) * (1.f / NBQ));
    }
}

// ---------------------------------------------------------------------------
extern "C" void kernel_launch(void* const* d_in, const int* in_sizes, int n_in,
                              void* d_out, int out_size, void* d_ws, size_t ws_size,
                              hipStream_t stream)
{
    const float* sup = (const float*)d_in[0];   // [4][25][640][121]
    const float* qry = (const float*)d_in[1];   // [4][75][640][121]
    const int*   qy  = (const int*)d_in[3];     // [4][75]
    float* out = (float*)d_out;
    float* ws  = (float*)d_ws;

    __hip_bfloat16* Sbf = (__hip_bfloat16*)(ws + OFF_SBF);
    __hip_bfloat16* Qbf = (__hip_bfloat16*)(ws + OFF_QBF);
    float4* pout = (float4*)(ws + OFF_P);
    float*  nrm  = (float*)(ws + OFF_NRM);   // aliases pout region (dead by then)

    hipLaunchKernelGGL(norm_kernel,  dim3((BB * SS + NBQ) * 4), dim3(128), 0, stream,
                       sup, qry, nrm, out);
    hipLaunchKernelGGL(scale_kernel, dim3((BB * SS + NBQ) * 4), dim3(256), 0, stream,
                       sup, qry, nrm, Sbf, Qbf);
    hipLaunchKernelGGL(simi_kernel, dim3(8 * BQ_PER_XCD * NW), dim3(256), 0, stream,
                       Sbf, Qbf, pout);
    hipLaunchKernelGGL(merge_kernel, dim3(NBQ), dim3(128), 0, stream, pout, qy, out);
}

// Round 10
// 393.205 us; speedup vs baseline: 1.0346x; 1.0231x over previous
//
#include <hip/hip_runtime.h>
#include <hip/hip_bf16.h>
#include <math.h>

#define BB 4
#define QQ 75
#define NBQ 300        // BB*QQ
#define CC 640
#define HW 121
#define NW 5
#define KS 5
#define SS 25          // NW*KS
#define MS 605         // KS*HW
#define JT 3025        // NW*MS
#define NPAIR 38       // query pairs per episode (75 -> 37 full + 1 dup)
#define PAIRS_PER_XCD 19  // 152 pairs / 8 XCDs

typedef __attribute__((ext_vector_type(8))) short short8;
typedef __attribute__((ext_vector_type(4))) float f32x4;

// workspace float offsets
#define OFF_SBF   0
#define SBF_F     (BB*JT*CC/2)            // bf16 storage
#define OFF_QBF   (OFF_SBF + SBF_F)
#define QBF_F     (NBQ*HW*CC/2)
#define OFF_P     (OFF_QBF + QBF_F)       // float4 partials [300][5][121]
// norm partials [400][4][128] f32 alias the pout region (dead until simi)
#define OFF_NRM   OFF_P

__device__ __forceinline__ void async16(const void* g, void* l) {
    __builtin_amdgcn_global_load_lds(
        (const __attribute__((address_space(1))) unsigned int*)g,
        (__attribute__((address_space(3))) unsigned int*)l, 16, 0, 0);
}

// ---------------------------------------------------------------------------
// Prep split (R5): wide-grid norm partials + scale/transpose/bf16 pack.
// Bit-exact with the original: (A0+A2)+(A1+A3) == old T[0]+T[1].
__global__ void norm_kernel(const float* __restrict__ sup, const float* __restrict__ qry,
                            float* __restrict__ nrm, float* __restrict__ out)
{
    const int blk = blockIdx.x;          // 0..1599 = col*4 + r
    const int col = blk >> 2, r = blk & 3;
    const int hw  = threadIdx.x;         // 128
    if (blk == 0 && hw == 0) out[0] = 0.f;   // replaces memset dispatch
    const float* src = (col < BB * SS)
        ? sup + (size_t)col * (CC * HW)
        : qry + (size_t)(col - BB * SS) * (CC * HW);
    float ss = 0.f;
    if (hw < HW) {
        const float* p = src + hw;
#pragma unroll 16
        for (int i = 0; i < CC / 4; ++i) {
            const float v = p[(size_t)(r + i * 4) * HW];
            ss = fmaf(v, v, ss);
        }
    }
    nrm[((size_t)col * 4 + r) * 128 + hw] = ss;
}

__global__ void scale_kernel(const float* __restrict__ sup, const float* __restrict__ qry,
                             const float* __restrict__ nrm,
                             __hip_bfloat16* __restrict__ Sbf, __hip_bfloat16* __restrict__ Qbf)
{
    const int blk = blockIdx.x;      // 0..1599 = col*4 + qtr
    const int col = blk >> 2, qtr = blk & 3;
    const int t   = threadIdx.x;     // 256
    const float* src;
    __hip_bfloat16* dst;
    if (col < BB * SS) {
        const int b = col / SS, s = col % SS;
        const int n = s / KS, k = s % KS;
        src = sup + (size_t)col * (CC * HW);
        dst = Sbf + ((size_t)b * JT + n * MS + k * HW) * CC;
    } else {
        const int bq = col - BB * SS;
        src = qry + (size_t)bq * (CC * HW);
        dst = Qbf + (size_t)bq * (HW * CC);
    }

    __shared__ float inv[128];
    __shared__ float T[32][128];

    if (t < 128) {
        const float p0 = nrm[((size_t)col * 4 + 0) * 128 + t];
        const float p1 = nrm[((size_t)col * 4 + 1) * 128 + t];
        const float p2 = nrm[((size_t)col * 4 + 2) * 128 + t];
        const float p3 = nrm[((size_t)col * 4 + 3) * 128 + t];
        inv[t] = (t < HW) ? 1.f / (sqrtf((p0 + p2) + (p1 + p3)) + 1e-8f) : 0.f;
    }

    for (int it = 0; it < 5; ++it) {
        const int c0 = qtr * 160 + it * 32;
        __syncthreads();                 // first pass also fences inv[]
#pragma unroll
        for (int i = 0; i < 16; ++i) {
            int idx = t + i * 256;
            int cc = idx >> 7, hw = idx & 127;
            if (hw < HW) T[cc][hw] = src[(size_t)(c0 + cc) * HW + hw] * inv[hw];
        }
        __syncthreads();
        const int hw = t >> 1, half = t & 1;
        if (hw < HW) {
            __hip_bfloat16 hv[16];
#pragma unroll
            for (int i = 0; i < 16; ++i) hv[i] = __float2bfloat16(T[half * 16 + i][hw]);
            int4* op = reinterpret_cast<int4*>(dst + (size_t)hw * CC + c0 + half * 16);
            op[0] = reinterpret_cast<int4*>(hv)[0];
            op[1] = reinterpret_cast<int4*>(hv)[1];
        }
    }
}

// ---------------------------------------------------------------------------
// R9: PAIRED-QUERY tile. Two queries of the same episode share the support
// panel, so one block computes m=256 (2 stacked bq, 121+pad each) x j=128
// with B staged ONCE: 24 KB/chunk for 2x the output (-25% staged bytes and
// -25% barrier-walls per MFMA; B HBM traffic halves). 512 thr = 8 waves,
// wave tile 64m x 64j (acc 64 AGPR), __launch_bounds__(512,4) -> 2 blocks/CU
// (16 waves). bf fragments read one-ahead (not [4]-resident) to fit the 128
// combined-reg cap. Triple-buffer + single barrier per chunk (R8-verified
// hazard proof: STAGE(t+1) issued after BAR(t-1); readers of that buffer were
// compute(t-2), retired before any wave reached BAR(t-1)). Transposed
// epilogue (R4): D[j,m] -> lane-local top-3 over j, 4 m-slots/lane.
__launch_bounds__(512, 4)
__global__ void simi_kernel(const __hip_bfloat16* __restrict__ Sbf,
                            const __hip_bfloat16* __restrict__ Qbf,
                            float4* __restrict__ pout)
{
    const int xcd   = blockIdx.x & 7;
    const int local = blockIdx.x >> 3;          // 0..94
    const int n     = local % NW;
    const int pair  = xcd * PAIRS_PER_XCD + local / NW;   // 0..151
    const int b     = pair / NPAIR;
    const int pi    = pair % NPAIR;
    const bool dup  = (pi == NPAIR - 1);        // 38th pair: q1 duplicates q0
    const int q0    = 2 * pi;
    const int q1    = dup ? q0 : q0 + 1;
    const int bq0   = b * QQ + q0;
    const int bq1   = b * QQ + q1;

    const int tid  = threadIdx.x;
    const int lane = tid & 63, wid = tid >> 6;  // 8 waves
    const int l15 = lane & 15, l4 = lane >> 4;
    const int wm0 = (wid >> 1) * 64;   // wave query-col base (0,64,128,192)
    const int wj0 = (wid & 1) * 64;    // wave support-row base (0,64)

    const unsigned short* qb0 = (const unsigned short*)(Qbf + (size_t)bq0 * (HW * CC));
    const unsigned short* qb1 = (const unsigned short*)(Qbf + (size_t)bq1 * (HW * CC));
    const unsigned short* sbase = (const unsigned short*)(Sbf + ((size_t)b * JT + n * MS) * CC);

    __shared__ __align__(16) unsigned short AsBuf[3][256 * 32];  // query tile, 3 x 16 KB
    __shared__ __align__(16) unsigned short BsBuf[3][128 * 32];  // support tile, 3 x 8 KB

    const int srow = lane >> 2;                       // row within 16-row group
    const int kb   = (lane & 3) ^ ((lane >> 3) & 3);  // swizzled k-block (0..3)

    // A: this wave stages rows wid*32 .. wid*32+31 (2 groups of 16)
    const unsigned short* aptr[2];
#pragma unroll
    for (int g = 0; g < 2; ++g) {
        int arow = wid * 32 + g * 16 + srow;          // 0..255
        int ml = arow & 127; ml = ml < HW ? ml : HW - 1;
        aptr[g] = ((arow >> 7) ? qb1 : qb0) + ml * CC + kb * 8;
    }
    // B: this wave stages rows wid*16 .. wid*16+15
    const int jrow = wid * 16 + srow;                 // 0..127
    const int ldsoA0 = wid * 2048 + lane * 16;
    const int ldsoA1 = ldsoA0 + 1024;
    const int ldsoB  = wid * 1024 + lane * 16;

    // stage one (ms0, c0) chunk (k=32): 3 async16 per wave (2 A + 1 B)
#define STAGE(ms0_, c0_, nb_)                                                        \
    {                                                                                \
        async16(aptr[0] + (c0_), (char*)&AsBuf[nb_][0] + ldsoA0);                    \
        async16(aptr[1] + (c0_), (char*)&AsBuf[nb_][0] + ldsoA1);                    \
        int j_ = (ms0_) + jrow;                                                      \
        int jc_ = j_ < MS ? j_ : MS - 1;                                             \
        async16(sbase + jc_ * CC + kb * 8 + (c0_), (char*)&BsBuf[nb_][0] + ldsoB);   \
    }

    // per-lane top-3 state: 4 m-slots (transposed epilogue)
    float rt0[4], rt1[4], rt2[4]; int ra[4];
#pragma unroll
    for (int i = 0; i < 4; ++i) { rt0[i] = -INFINITY; rt1[i] = -INFINITY; rt2[i] = -INFINITY; ra[i] = 0; }

    f32x4 acc[4][4];   // [ji][qi]
#pragma unroll
    for (int ji = 0; ji < 4; ++ji)
#pragma unroll
        for (int qi = 0; qi < 4; ++qi)
#pragma unroll
            for (int r = 0; r < 4; ++r) acc[ji][qi][r] = 0.f;

    STAGE(0, 0, 0);
    int nb = 0;

    const int slot = l4 ^ ((l15 >> 1) & 3);           // read slot (0..3)
    const int aro  = (wm0 + l15) * 32 + slot * 8;     // ushort idx, + qi*512
    const int bro  = (wj0 + l15) * 32 + slot * 8;     // ushort idx, + ji*512

    // flat pipelined loop: chunk t -> ms0=(t/20)*128, c0=(t%20)*32
    for (int t = 0; t < 100; ++t) {
        const int tn = t + 1;
        const int nxt = (nb == 2) ? 0 : nb + 1;
        if (tn < 100) {
            const int nms = (tn / 20) * 128;
            const int nc  = (tn % 20) * 32;
            STAGE(nms, nc, nxt);
            // wait only for chunk-t's 3 loads (issued one full chunk ago)
            asm volatile("s_waitcnt vmcnt(3)" ::: "memory");
        } else {
            asm volatile("s_waitcnt vmcnt(0)" ::: "memory");
        }
        __builtin_amdgcn_s_barrier();   // buffer nb fully resident for all waves

        // ---- compute: af[4] resident; bf read one-ahead (reg-cap friendly) ----
        short8 af[4];
#pragma unroll
        for (int qi = 0; qi < 4; ++qi)
            af[qi] = *(const short8*)(&AsBuf[nb][0] + aro + qi * 512);

        short8 bfA = *(const short8*)(&BsBuf[nb][0] + bro);
        __builtin_amdgcn_s_setprio(1);
#pragma unroll
        for (int ji = 0; ji < 4; ++ji) {
            short8 bfB;
            if (ji < 3) bfB = *(const short8*)(&BsBuf[nb][0] + bro + (ji + 1) * 512);
#pragma unroll
            for (int qi = 0; qi < 4; ++qi)
                acc[ji][qi] = __builtin_amdgcn_mfma_f32_16x16x32_bf16(
                    bfA, af[qi], acc[ji][qi], 0, 0, 0);   // D[j, m]
            bfA = bfB;
        }
        __builtin_amdgcn_s_setprio(0);
        nb = nxt;

        if ((t % 20) == 19) {
            const int ms0 = (t / 20) * 128;
            // lane-local top-3; (ji,r) ascending == j ascending; strict >
            // keeps the first (smallest-j) max.
#pragma unroll
            for (int qi = 0; qi < 4; ++qi)
#pragma unroll
                for (int ji = 0; ji < 4; ++ji)
#pragma unroll
                    for (int r = 0; r < 4; ++r) {
                        const int jl = ms0 + wj0 + ji * 16 + l4 * 4 + r;
                        float v = (jl < MS) ? acc[ji][qi][r] : -INFINITY;
                        const bool gt = v > rt0[qi];
                        ra[qi] = gt ? (n * MS + jl) : ra[qi];
                        const float m1 = fminf(rt0[qi], v);
                        rt0[qi] = fmaxf(rt0[qi], v);
                        const float m2 = fminf(rt1[qi], m1);
                        rt1[qi] = fmaxf(rt1[qi], m1);
                        rt2[qi] = fmaxf(rt2[qi], m2);
                    }
#pragma unroll
            for (int ji = 0; ji < 4; ++ji)
#pragma unroll
                for (int qi = 0; qi < 4; ++qi)
#pragma unroll
                    for (int r = 0; r < 4; ++r) acc[ji][qi][r] = 0.f;
        }
    }

    // cross-l4 butterfly (masks 16,32): merge the 4 j-interleaved partitions
#pragma unroll
    for (int qi = 0; qi < 4; ++qi) {
#pragma unroll
        for (int mask = 16; mask <= 32; mask <<= 1) {
            const float o0 = __shfl_xor(rt0[qi], mask);
            const float o1 = __shfl_xor(rt1[qi], mask);
            const float o2 = __shfl_xor(rt2[qi], mask);
            const int   oa = __shfl_xor(ra[qi],  mask);
            const bool take = (o0 > rt0[qi]) || (o0 == rt0[qi] && oa < ra[qi]);
            ra[qi] = take ? oa : ra[qi];
            float m1 = fminf(rt0[qi], o0); rt0[qi] = fmaxf(rt0[qi], o0);
            float m2 = fminf(rt1[qi], m1); rt1[qi] = fmaxf(rt1[qi], m1);
            rt2[qi] = fmaxf(rt2[qi], m2);
            m1 = fminf(rt0[qi], o1); rt0[qi] = fmaxf(rt0[qi], o1);
            m2 = fminf(rt1[qi], m1); rt1[qi] = fmaxf(rt1[qi], m1);
            rt2[qi] = fmaxf(rt2[qi], m2);
            m1 = fminf(rt0[qi], o2); rt0[qi] = fmaxf(rt0[qi], o2);
            m2 = fminf(rt1[qi], m1); rt1[qi] = fmaxf(rt1[qi], m1);
            rt2[qi] = fmaxf(rt2[qi], m2);
        }
    }

    // cross-wave merge: waves (2w, 2w+1) share wm0, hold disjoint j-halves.
    // Tie rule is encoded in the index compare (oa < sa) -> order-independent.
    __syncthreads();                       // all tile reads done -> safe overlay
    float4* mbuf = (float4*)&AsBuf[0][0];  // 256 float4 = 4 KB
    if ((wid & 1) == 0 && l4 == 0) {
#pragma unroll
        for (int qi = 0; qi < 4; ++qi) {
            float4 v; v.x = rt0[qi]; v.y = rt1[qi]; v.z = rt2[qi];
            v.w = __int_as_float(ra[qi]);
            mbuf[wm0 + qi * 16 + l15] = v;
        }
    }
    __syncthreads();
    if ((wid & 1) == 1 && l4 == 0) {
#pragma unroll
        for (int qi = 0; qi < 4; ++qi) {
            const int m = wm0 + qi * 16 + l15;      // 0..255
            const float4 o = mbuf[m];
            const int oa = __float_as_int(o.w);
            float s0 = rt0[qi], s1 = rt1[qi], s2 = rt2[qi]; int sa = ra[qi];
            const bool take = (o.x > s0) || (o.x == s0 && oa < sa);
            sa = take ? oa : sa;
            float m1 = fminf(s0, o.x); s0 = fmaxf(s0, o.x);
            float m2 = fminf(s1, m1);  s1 = fmaxf(s1, m1);
            s2 = fmaxf(s2, m2);
            m1 = fminf(s0, o.y); s0 = fmaxf(s0, o.y);
            m2 = fminf(s1, m1);  s1 = fmaxf(s1, m1);
            s2 = fmaxf(s2, m2);
            m1 = fminf(s0, o.z); s0 = fmaxf(s0, o.z);
            m2 = fminf(s1, m1);  s1 = fmaxf(s1, m1);
            s2 = fmaxf(s2, m2);
            const int bqs = m >> 7;                 // which query of the pair
            const int ml  = m & 127;
            if (ml < HW && (bqs == 0 || !dup)) {
                const int bqx = bqs ? bq1 : bq0;
                float4 v; v.x = s0; v.y = s1; v.z = s2; v.w = __int_as_float(sa);
                pout[(bqx * NW + n) * HW + ml] = v;
            }
        }
    }
#undef STAGE
}

// ---------------------------------------------------------------------------
// Merge 5 per-n partials, mutual-NN mask, logits, per-query CE, atomic mean.
__global__ void merge_kernel(const float4* __restrict__ pout, const int* __restrict__ qy,
                             float* __restrict__ out)
{
    const int bq  = blockIdx.x;
    const int tid = threadIdx.x;   // 128 threads

    __shared__ float cw[128];
    __shared__ int   ag[128];
    __shared__ float tv[NW][128];
    __shared__ float maskf[128];
    __shared__ float lg[8];

    if (tid < HW) {
        float g0 = -INFINITY; int garg = 0;
#pragma unroll
        for (int n = 0; n < NW; ++n) {
            const float4 a = pout[(bq * NW + n) * HW + tid];
            if (a.x > g0) { g0 = a.x; garg = __float_as_int(a.w); }   // asc n = asc j
            tv[n][tid] = (a.x + a.y + a.z) * (1.f / 3.f);
        }
        cw[tid] = g0 + 1.0f;   // class_wise_max
        ag[tid] = garg;        // query_nearest (global j)
    }
    __syncthreads();
    if (tid < HW) {
        const float mycw = cw[tid];
        const int   myag = ag[tid];
        float ok = 1.f;
        for (int m2 = 0; m2 < HW; ++m2) {
            if (m2 == tid) continue;
            if (ag[m2] == myag) {
                float c2 = cw[m2];
                if (c2 > mycw || (c2 == mycw && m2 < tid)) ok = 0.f;  // first-max over mq
            }
        }
        maskf[tid] = ok;
    }
    __syncthreads();
    if (tid < NW) {
        float s = 0.f;
        for (int mq = 0; mq < HW; ++mq) s += maskf[mq] * tv[tid][mq];
        lg[tid] = s * 0.5f;   // / TEMPERATURE
    }
    __syncthreads();
    if (tid == 0) {
        float m = lg[0];
#pragma unroll
        for (int n2 = 1; n2 < NW; ++n2) m = fmaxf(m, lg[n2]);
        float se = 0.f;
#pragma unroll
        for (int n2 = 0; n2 < NW; ++n2) se += expf(lg[n2] - m);
        int y = qy[bq];
        atomicAdd(out, -(lg[y] - m - logf(se)) * (1.f / NBQ));
    }
}

// ---------------------------------------------------------------------------
extern "C" void kernel_launch(void* const* d_in, const int* in_sizes, int n_in,
                              void* d_out, int out_size, void* d_ws, size_t ws_size,
                              hipStream_t stream)
{
    const float* sup = (const float*)d_in[0];   // [4][25][640][121]
    const float* qry = (const float*)d_in[1];   // [4][75][640][121]
    const int*   qy  = (const int*)d_in[3];     // [4][75]
    float* out = (float*)d_out;
    float* ws  = (float*)d_ws;

    __hip_bfloat16* Sbf = (__hip_bfloat16*)(ws + OFF_SBF);
    __hip_bfloat16* Qbf = (__hip_bfloat16*)(ws + OFF_QBF);
    float4* pout = (float4*)(ws + OFF_P);
    float*  nrm  = (float*)(ws + OFF_NRM);   // aliases pout region (dead by then)

    hipLaunchKernelGGL(norm_kernel,  dim3((BB * SS + NBQ) * 4), dim3(128), 0, stream,
                       sup, qry, nrm, out);
    hipLaunchKernelGGL(scale_kernel, dim3((BB * SS + NBQ) * 4), dim3(256), 0, stream,
                       sup, qry, nrm, Sbf, Qbf);
    hipLaunchKernelGGL(simi_kernel, dim3(8 * PAIRS_PER_XCD * NW), dim3(512), 0, stream,
                       Sbf, Qbf, pout);
    hipLaunchKernelGGL(merge_kernel, dim3(NBQ), dim3(128), 0, stream, pout, qy, out);
}